// Round 3
// baseline (163.259 us; speedup 1.0000x reference)
//
#include <hip/hip_runtime.h>
#include <math.h>

#define CC 512
#define HH 38
#define WW 63
#define HWSZ (HH * WW)
#define NROIS 1024
#define NP 49            // 7x7 pooled positions

typedef float f32x4 __attribute__((ext_vector_type(4)));

static __device__ __forceinline__ f32x4 splat4(float v) {
    f32x4 r; r[0] = v; r[1] = v; r[2] = v; r[3] = v; return r;
}

// ---------------- LDS-tiled transpose: CHW (512, 2394) -> HWC (2394, 512) ----
__global__ __launch_bounds__(256) void transpose_tiled(
        const float* __restrict__ src, float* __restrict__ dst) {
    __shared__ float tile[64][65];
    int s0 = blockIdx.x * 64;
    int c0 = blockIdx.y * 64;
    int tx = threadIdx.x & 63;
    int ty = threadIdx.x >> 6;

#pragma unroll
    for (int k = 0; k < 16; ++k) {
        int c = ty * 16 + k;
        int s = s0 + tx;
        float v = (s < HWSZ) ? src[(c0 + c) * HWSZ + s] : 0.0f;
        tile[tx][c] = v;
    }
    __syncthreads();
#pragma unroll
    for (int k = 0; k < 16; ++k) {
        int s = ty * 16 + k;
        if (s0 + s < HWSZ)
            dst[(s0 + s) * CC + c0 + tx] = tile[s][tx];
    }
}

// ---------------- main kernel v8 ---------------------------------------------
// v7 structure (quarter-roi, 256 thr, lane g = channel-quad, slot s = output
// row, channel-major stride-49 stage, linear nontemporal flush) + the MLP fix:
// v7's VGPR=40 meant only ~6 gathers in flight -> ~28 dependent latency
// round-trips per thread against L2/L3 (~250 cy); dispatch was ~50% stall.
// v8 issues ALL 16 corner gathers of an output position as one straight-line
// batch into named registers before any interp math: 16 loads in flight per
// wave, one vmcnt wait per ox. __launch_bounds__(256,4) caps VGPR at 128
// (4 waves/SIMD = the 16 waves/CU we already measured -> occupancy not
// traded), payload 64 VGPR + ~40 misc fits without spills.
__global__ __launch_bounds__(256, 4) void roi_pool_v8(
        const float* __restrict__ img,    // HWC (2394, 512)
        const float* __restrict__ rois,   // (N, 5)
        float* __restrict__ out) {        // (N, 512, 7, 7)
    __shared__ float stage[128 * NP];     // 25088 B

    int n = blockIdx.x >> 2;              // wave-uniform
    int q = blockIdx.x & 3;
    int t = threadIdx.x;
    int g = t & 31;                       // channel-quad within quarter
    int s = t >> 5;                       // row slot 0..7 (slot 7 idle)

    const float* r = rois + n * 5;
    float x1n = (r[1] * 0.0625f) / 62.0f;
    float y1n = (r[2] * 0.0625f) / 37.0f;
    float x2n = (r[3] * 0.0625f) / 62.0f;
    float y2n = (r[4] * 0.0625f) / 37.0f;
    float ydn = y2n - y1n;
    float xdn = x2n - x1n;

    if (s < 7) {
        int oy = s;
        const f32x4* img4 = (const f32x4*)img + (q << 5) + g;

        // y-params for the two sample rows of this output row
        float wy0, wy1; int yA0, yB0, yA1, yB1; bool vy0, vy1;
        {
            float tty = (float)(oy * 2) * (1.0f / 13.0f);
            float in_y = (y1n + tty * ydn) * 37.0f;
            vy0 = (in_y >= 0.0f) && (in_y <= 37.0f);
            float y0f = floorf(in_y);
            wy0 = in_y - y0f;
            yA0 = (int)fminf(fmaxf(y0f, 0.0f), 37.0f) * (WW * (CC / 4));
            yB0 = (int)fminf(fmaxf(y0f + 1.0f, 0.0f), 37.0f) * (WW * (CC / 4));
        }
        {
            float tty = (float)(oy * 2 + 1) * (1.0f / 13.0f);
            float in_y = (y1n + tty * ydn) * 37.0f;
            vy1 = (in_y >= 0.0f) && (in_y <= 37.0f);
            float y0f = floorf(in_y);
            wy1 = in_y - y0f;
            yA1 = (int)fminf(fmaxf(y0f, 0.0f), 37.0f) * (WW * (CC / 4));
            yB1 = (int)fminf(fmaxf(y0f + 1.0f, 0.0f), 37.0f) * (WW * (CC / 4));
        }

        int sbase = g * (4 * NP) + oy * 7;   // stage float base for channel 4g

#pragma unroll
        for (int ox = 0; ox < 7; ++ox) {
            // ---- x-params for the two sample columns of this output ----
            float wxA, wxB; int x0A, x1A, x0B, x1B; bool vxA, vxB;
            {
                float ttx = (float)(ox * 2) * (1.0f / 13.0f);
                float in_x = (x1n + ttx * xdn) * 62.0f;
                vxA = (in_x >= 0.0f) && (in_x <= 62.0f);
                float x0f = floorf(in_x);
                wxA = in_x - x0f;
                x0A = (int)fminf(fmaxf(x0f, 0.0f), 62.0f) << 7;        // * CC/4
                x1A = (int)fminf(fmaxf(x0f + 1.0f, 0.0f), 62.0f) << 7;
            }
            {
                float ttx = (float)(ox * 2 + 1) * (1.0f / 13.0f);
                float in_x = (x1n + ttx * xdn) * 62.0f;
                vxB = (in_x >= 0.0f) && (in_x <= 62.0f);
                float x0f = floorf(in_x);
                wxB = in_x - x0f;
                x0B = (int)fminf(fmaxf(x0f, 0.0f), 62.0f) << 7;
                x1B = (int)fminf(fmaxf(x0f + 1.0f, 0.0f), 62.0f) << 7;
            }

            // ---- issue all 16 corner gathers as one batch (MLP=16) ----
            f32x4 a00 = img4[yA0 + x0A];   // sample (sxA, sy0)
            f32x4 a01 = img4[yA0 + x1A];
            f32x4 a10 = img4[yB0 + x0A];
            f32x4 a11 = img4[yB0 + x1A];
            f32x4 b00 = img4[yA1 + x0A];   // sample (sxA, sy1)
            f32x4 b01 = img4[yA1 + x1A];
            f32x4 b10 = img4[yB1 + x0A];
            f32x4 b11 = img4[yB1 + x1A];
            f32x4 c00 = img4[yA0 + x0B];   // sample (sxB, sy0)
            f32x4 c01 = img4[yA0 + x1B];
            f32x4 c10 = img4[yB0 + x0B];
            f32x4 c11 = img4[yB0 + x1B];
            f32x4 d00 = img4[yA1 + x0B];   // sample (sxB, sy1)
            f32x4 d01 = img4[yA1 + x1B];
            f32x4 d10 = img4[yB1 + x0B];
            f32x4 d11 = img4[yB1 + x1B];

            // ---- interp + max ----
            f32x4 acc = splat4(-INFINITY);
            {
                f32x4 top = a00 + (a01 - a00) * wxA;
                f32x4 bot = a10 + (a11 - a10) * wxA;
                f32x4 val = top + (bot - top) * wy0;
                val = (vxA && vy0) ? val : splat4(0.0f);
#pragma unroll
                for (int j = 0; j < 4; ++j) acc[j] = fmaxf(acc[j], val[j]);
            }
            {
                f32x4 top = b00 + (b01 - b00) * wxA;
                f32x4 bot = b10 + (b11 - b10) * wxA;
                f32x4 val = top + (bot - top) * wy1;
                val = (vxA && vy1) ? val : splat4(0.0f);
#pragma unroll
                for (int j = 0; j < 4; ++j) acc[j] = fmaxf(acc[j], val[j]);
            }
            {
                f32x4 top = c00 + (c01 - c00) * wxB;
                f32x4 bot = c10 + (c11 - c10) * wxB;
                f32x4 val = top + (bot - top) * wy0;
                val = (vxB && vy0) ? val : splat4(0.0f);
#pragma unroll
                for (int j = 0; j < 4; ++j) acc[j] = fmaxf(acc[j], val[j]);
            }
            {
                f32x4 top = d00 + (d01 - d00) * wxB;
                f32x4 bot = d10 + (d11 - d10) * wxB;
                f32x4 val = top + (bot - top) * wy1;
                val = (vxB && vy1) ? val : splat4(0.0f);
#pragma unroll
                for (int j = 0; j < 4; ++j) acc[j] = fmaxf(acc[j], val[j]);
            }

            // 4 scalar stage writes, compile-time offsets fold into ds imm
            stage[sbase + ox         ] = acc[0];
            stage[sbase + ox + NP    ] = acc[1];
            stage[sbase + ox + 2 * NP] = acc[2];
            stage[sbase + ox + 3 * NP] = acc[3];
        }
    }

    __syncthreads();

    // linear flush: stage float layout == output layout for this quarter.
    const f32x4* s4 = (const f32x4*)stage;
    f32x4* o4 = (f32x4*)(out + ((n << 9) + (q << 7)) * NP);
    for (int i = t; i < (128 * NP) / 4; i += 256)
        __builtin_nontemporal_store(s4[i], &o4[i]);
}

// ---------------- fallback (ws too small): direct CHW gathers ----------------
__global__ __launch_bounds__(256) void roi_pool_chw(
        const float* __restrict__ img,    // CHW
        const float* __restrict__ rois,
        float* __restrict__ out) {
    __shared__ float stage[256 * NP];
    int n = blockIdx.x >> 1;
    int h = blockIdx.x & 1;
    int t = threadIdx.x;
    int c = (h << 8) + t;

    const float* r = rois + n * 5;
    float x1n = (r[1] * 0.0625f) / 62.0f;
    float y1n = (r[2] * 0.0625f) / 37.0f;
    float x2n = (r[3] * 0.0625f) / 62.0f;
    float y2n = (r[4] * 0.0625f) / 37.0f;
    float ydn = y2n - y1n;
    float xdn = x2n - x1n;

    const float* imgc = img + c * HWSZ;

    float wxa[14];
    int   x0a[14], x1a[14];
    int   vxm = 0;
#pragma unroll
    for (int ix = 0; ix < 14; ++ix) {
        float tt = (float)ix * (1.0f / 13.0f);
        float in_x = (x1n + tt * xdn) * 62.0f;
        if (in_x >= 0.0f && in_x <= 62.0f) vxm |= (1 << ix);
        float x0f = floorf(in_x);
        wxa[ix] = in_x - x0f;
        x0a[ix] = (int)fminf(fmaxf(x0f, 0.0f), 62.0f);
        x1a[ix] = (int)fminf(fmaxf(x0f + 1.0f, 0.0f), 62.0f);
    }

#pragma unroll
    for (int oy = 0; oy < 7; ++oy) {
        float row[7];
#pragma unroll
        for (int ox = 0; ox < 7; ++ox) row[ox] = -INFINITY;
#pragma unroll
        for (int sy = 0; sy < 2; ++sy) {
            int iy = oy * 2 + sy;
            float tt = (float)iy * (1.0f / 13.0f);
            float in_y = (y1n + tt * ydn) * 37.0f;
            bool vy = (in_y >= 0.0f) && (in_y <= 37.0f);
            float y0f = floorf(in_y);
            float wy = in_y - y0f;
            int yy0 = (int)fminf(fmaxf(y0f, 0.0f), 37.0f);
            int yy1 = (int)fminf(fmaxf(y0f + 1.0f, 0.0f), 37.0f);
            int yb0 = yy0 * WW;
            int yb1 = yy1 * WW;
#pragma unroll
            for (int ox = 0; ox < 7; ++ox) {
#pragma unroll
                for (int sx = 0; sx < 2; ++sx) {
                    int ix = ox * 2 + sx;
                    float g00 = imgc[yb0 + x0a[ix]];
                    float g01 = imgc[yb0 + x1a[ix]];
                    float g10 = imgc[yb1 + x0a[ix]];
                    float g11 = imgc[yb1 + x1a[ix]];
                    float wx = wxa[ix];
                    float top = g00 + (g01 - g00) * wx;
                    float bot = g10 + (g11 - g10) * wx;
                    float val = top + (bot - top) * wy;
                    bool valid = vy && ((vxm >> ix) & 1);
                    val = valid ? val : 0.0f;
                    row[ox] = fmaxf(row[ox], val);
                }
            }
        }
#pragma unroll
        for (int ox = 0; ox < 7; ++ox)
            stage[t * NP + oy * 7 + ox] = row[ox];
    }

    __syncthreads();
    const float4* s4 = (const float4*)stage;
    float4* o4 = (float4*)(out + ((n << 9) + (h << 8)) * NP);
    for (int i = t; i < (256 * NP) / 4; i += 256)
        o4[i] = s4[i];
}

extern "C" void kernel_launch(void* const* d_in, const int* in_sizes, int n_in,
                              void* d_out, int out_size, void* d_ws, size_t ws_size,
                              hipStream_t stream) {
    const float* bottom = (const float*)d_in[0];
    const float* rois   = (const float*)d_in[1];
    float* out = (float*)d_out;

    const size_t need = (size_t)CC * HWSZ * sizeof(float);  // ~4.9 MB
    if (ws_size >= need) {
        float* img = (float*)d_ws;
        dim3 tg((HWSZ + 63) / 64, CC / 64);   // 38 x 8
        transpose_tiled<<<tg, 256, 0, stream>>>(bottom, img);
        roi_pool_v8<<<NROIS * 4, 256, 0, stream>>>(img, rois, out);
    } else {
        roi_pool_chw<<<NROIS * 2, 256, 0, stream>>>(bottom, rois, out);
    }
}